// Round 1
// baseline (145.158 us; speedup 1.0000x reference)
//
#include <hip/hip_runtime.h>
#include <hip/hip_bf16.h>

#define Bdim 2
#define Hdim 16
#define Sdim 2048
#define Ddim 64
#define KVB 64
#define NT (Sdim / KVB)

typedef __attribute__((ext_vector_type(4)))  float    f32x4;
typedef __attribute__((ext_vector_type(16))) float    f32x16;
typedef __attribute__((ext_vector_type(2)))  unsigned u32x2;
typedef __attribute__((ext_vector_type(4)))  unsigned u32x4;
typedef __attribute__((ext_vector_type(8)))  short    s16x8;

#define NEGM   (-1.0e30f)
#define M_INIT (-30000.0f)
#define QS     0.18033688011112042f   // 0.125 * log2(e), folded into Q
#define L2E    1.4426950408889634f
#define THR    11.5f                  // defer-max threshold (log2 units ~ 8 nats)

typedef __attribute__((address_space(1))) void gv_t;
typedef __attribute__((address_space(3))) void lv_t;

// packed fp32x2 -> bf16x2 (RNE) — compiler emits v_cvt_pk_bf16_f32
static __device__ __forceinline__ unsigned pk2(float lo, float hi) {
  float2 t; t.x = lo; t.y = hi;
  __hip_bfloat162 h = __float22bfloat162_rn(t);
  unsigned u; __builtin_memcpy(&u, &h, 4); return u;
}

static __device__ __forceinline__ void pl32swap(unsigned a, unsigned b,
                                                unsigned &x, unsigned &y) {
#if __has_builtin(__builtin_amdgcn_permlane32_swap)
  typedef unsigned uv2 __attribute__((ext_vector_type(2)));
  uv2 r = __builtin_amdgcn_permlane32_swap(a, b, false, false);
  x = r[0]; y = r[1];
#else
  unsigned pa = (unsigned)__shfl_xor((int)a, 32);
  unsigned pb = (unsigned)__shfl_xor((int)b, 32);
  bool hi = (threadIdx.x & 32) != 0;
  x = hi ? pb : a;
  y = hi ? b : pa;
#endif
}

// ---------------- pre-pass: K/V^T -> bf16 fragment-linear tile images ------
// Image layout per (bh, jt): 512 chunks of 16B. chunk c: blk=c>>6, l=c&63.
// K  (blk = sub*4+kc): holds K [j=32sub+(l&31)] [elems 16kc+8(l>>5) .. +8]
// V^T(blk = dn*4+jc):  holds V^T[d=32dn+(l&31)] [j-elems 16jc+8(l>>5) .. +8]
__global__ __launch_bounds__(256, 2)
void pack_kernel(const float* __restrict__ k, const float* __restrict__ v,
                 const int* __restrict__ mask,
                 unsigned short* __restrict__ kimg,
                 unsigned short* __restrict__ vimg,
                 float* __restrict__ mneg)
{
  const int jt = blockIdx.x;   // 0..31
  const int bh = blockIdx.y;   // 0..31
  const int tid = threadIdx.x;
  const size_t base = ((size_t)bh) * Sdim * Ddim + (size_t)jt * KVB * Ddim;

  // K pack (2 chunks/thread)
  unsigned short* kout = kimg + ((size_t)(bh * NT + jt)) * 4096;
#pragma unroll
  for (int cc = 0; cc < 2; ++cc) {
    int c = tid + cc * 256;
    int blk = c >> 6, l = c & 63;
    int sub = blk >> 2, kc = blk & 3;
    int j = 32 * sub + (l & 31), e0 = 16 * kc + 8 * (l >> 5);
    const float* src = k + base + j * 64 + e0;
    f32x4 a = *(const f32x4*)src, b2 = *(const f32x4*)(src + 4);
    u32x4 t;
    t[0] = pk2(a[0], a[1]);  t[1] = pk2(a[2], a[3]);
    t[2] = pk2(b2[0], b2[1]); t[3] = pk2(b2[2], b2[3]);
    *(u32x4*)(kout + (size_t)c * 8) = t;
  }

  // V transpose pack via LDS
  __shared__ float Vl[64 * 64];
  {
    int r = tid >> 2, c4 = (tid & 3) * 16;
    const float* src = v + base + r * 64 + c4;
#pragma unroll
    for (int i = 0; i < 4; ++i)
      *(f32x4*)&Vl[r * 64 + c4 + 4 * i] = *(const f32x4*)(src + 4 * i);
  }
  __syncthreads();
  unsigned short* vout = vimg + ((size_t)(bh * NT + jt)) * 4096;
#pragma unroll
  for (int cc = 0; cc < 2; ++cc) {
    int c = tid + cc * 256;
    int blk = c >> 6, l = c & 63;
    int dn = blk >> 2, jc = blk & 3;
    int d = 32 * dn + (l & 31), jl0 = 16 * jc + 8 * (l >> 5);
    u32x4 t;
#pragma unroll
    for (int p = 0; p < 4; ++p)
      t[p] = pk2(Vl[(jl0 + 2 * p) * 64 + d], Vl[(jl0 + 2 * p + 1) * 64 + d]);
    *(u32x4*)(vout + (size_t)c * 8) = t;
  }

  // mneg
  if ((bh & 15) == 0 && tid < 64) {
    int b = bh >> 4;
    int j = jt * KVB + tid;
    mneg[b * Sdim + j] = mask[b * Sdim + j] ? 0.0f : NEGM;
  }
}

// ---------------- main kernel ----------------------------------------------
// 4 waves/block, 32 q-rows per wave. 32x32x16 MFMA, swapped operands.
// K/V^T staged via global_load_lds (16B async DMA) from fragment-linear
// images; double-buffered. Bias/mneg loads for tile jt+1 are issued at the
// top of tile jt and kept in flight across the barrier with a COUNTED
// s_waitcnt vmcnt(16) (16 newest = next-tile addv loads stay outstanding;
// the 20 oldest = this tile's addv + this tile's K/V DMA complete). Raw
// s_barrier (not __syncthreads) so the compiler can't reinstate a vmcnt(0)
// drain. Each tile's addv loads thus get a full tile of compute as latency
// cover instead of stalling the barrier every tile.
__global__ __launch_bounds__(256, 2)
void attn_kernel(const float* __restrict__ q,
                 unsigned short* __restrict__ kimg,
                 unsigned short* __restrict__ vimg,
                 const float* __restrict__ mneg,
                 const float* __restrict__ taus, const float* __restrict__ bias,
                 float* __restrict__ out)
{
  const int tid  = threadIdx.x;
  const int wave = tid >> 6;
  const int lane = tid & 63;
  const int h2   = lane >> 5;
  const int q5   = lane & 31;

  const int bh = blockIdx.y;
  const int b  = bh >> 4, h = bh & 15;
  const int iw = blockIdx.x * 128 + wave * 32;
  const int qr = iw + q5;

  __shared__ __align__(16) unsigned short Kl[2][4096];
  __shared__ __align__(16) unsigned short Vt[2][4096];

  const float ntau = -taus[h] * L2E;
  const size_t qkvbase = ((size_t)bh) * Sdim * Ddim;
  const float* biasb = bias + (size_t)b * Sdim * Sdim + (size_t)qr * Sdim;
  const float* mnegb = mneg + b * Sdim;

  // Q B-fragments: qf[kc] = Q[qr][16kc + 8h2 + t]*QS
  s16x8 qf[4];
  {
    const float* qrow = q + qkvbase + (size_t)qr * Ddim + 8 * h2;
#pragma unroll
    for (int kc = 0; kc < 4; ++kc) {
      f32x4 a = *(const f32x4*)(qrow + 16 * kc);
      f32x4 c = *(const f32x4*)(qrow + 16 * kc + 4);
      u32x4 t;
      t[0] = pk2(a[0] * QS, a[1] * QS); t[1] = pk2(a[2] * QS, a[3] * QS);
      t[2] = pk2(c[0] * QS, c[1] * QS); t[3] = pk2(c[2] * QS, c[3] * QS);
      s16x8 f; __builtin_memcpy(&f, &t, 16); qf[kc] = f;
    }
  }

  // async stage tile jt into buffer buf: 4 global_load_lds per wave
  auto stage = [&](int jt, int buf) {
    size_t tb = ((size_t)(bh * NT + jt)) * 4096 + wave * 1024 + lane * 8;
    int lo = wave * 1024;
#pragma unroll
    for (int i = 0; i < 2; ++i) {
      __builtin_amdgcn_global_load_lds((gv_t*)(kimg + tb + i * 512),
                                       (lv_t*)&Kl[buf][lo + i * 512], 16, 0, 0);
      __builtin_amdgcn_global_load_lds((gv_t*)(vimg + tb + i * 512),
                                       (lv_t*)&Vt[buf][lo + i * 512], 16, 0, 0);
    }
  };

  f32x16 O[2];
  O[0] = (f32x16)(0.0f); O[1] = (f32x16)(0.0f);
  float m = M_INIT, l = 0.0f;

  // bias/mneg prefetch register sets (ping-pong A/B, all static indexing)
  f32x4 bvA[2][4], mnA[2][4], bvB[2][4], mnB[2][4];

  stage(0, 0);
  // prologue: issue addv loads for tile 0 into set A (16 loads in flight)
#pragma unroll
  for (int sub = 0; sub < 2; ++sub)
#pragma unroll
    for (int c = 0; c < 4; ++c) {
      int gj = 32 * sub + 8 * c + 4 * h2;
      bvA[sub][c] = *(const f32x4*)(biasb + gj);
      mnA[sub][c] = *(const f32x4*)(mnegb + gj);
    }

  auto body = [&](int jt, f32x4 (&bvC)[2][4], f32x4 (&mnC)[2][4],
                  f32x4 (&bvN)[2][4], f32x4 (&mnN)[2][4]) {
    const int cur = jt & 1;

    // ---- issue next tile's bias/mneg loads; counted wait keeps them flying
    if (jt + 1 < NT) {
      const int j0n = (jt + 1) * KVB;
#pragma unroll
      for (int sub = 0; sub < 2; ++sub)
#pragma unroll
        for (int c = 0; c < 4; ++c) {
          int gj = j0n + 32 * sub + 8 * c + 4 * h2;
          bvN[sub][c] = *(const f32x4*)(biasb + gj);
          mnN[sub][c] = *(const f32x4*)(mnegb + gj);
        }
      // outstanding: [addv_cur 16, DMA_cur 4, addv_next 16] -> wait oldest 20
      asm volatile("s_waitcnt vmcnt(16)" ::: "memory");
    } else {
      asm volatile("s_waitcnt vmcnt(0)" ::: "memory");
    }
    __builtin_amdgcn_s_barrier();          // raw barrier: no implicit drain
    if (jt + 1 < NT) stage(jt + 1, cur ^ 1);

    // ---- fold addv now (bvC/mnC complete); frees prefetch regs early ----
    f32x4 addv[2][4];
#pragma unroll
    for (int sub = 0; sub < 2; ++sub)
#pragma unroll
      for (int c = 0; c < 4; ++c)
        addv[sub][c] = ntau * bvC[sub][c] + mnC[sub][c];

    // ---- QK^T: acc[sub] = S^T[j][q], log2-scaled ----
    const unsigned short* kb = &Kl[cur][0];
    f32x16 acc[2];
    acc[0] = (f32x16)(0.0f); acc[1] = (f32x16)(0.0f);
    __builtin_amdgcn_s_setprio(1);
#pragma unroll
    for (int sub = 0; sub < 2; ++sub)
#pragma unroll
      for (int kc = 0; kc < 4; ++kc) {
        s16x8 kf = *(const s16x8*)(kb + (sub * 4 + kc) * 512 + lane * 8);
        acc[sub] = __builtin_amdgcn_mfma_f32_32x32x16_bf16(kf, qf[kc], acc[sub], 0, 0, 0);
      }
    __builtin_amdgcn_s_setprio(0);

    // ---- scores (log2 domain) ----
    float s[32];
#pragma unroll
    for (int sub = 0; sub < 2; ++sub)
#pragma unroll
      for (int r = 0; r < 16; ++r)
        s[16 * sub + r] = acc[sub][r] + addv[sub][r >> 2][r & 3];

    // ---- online softmax over 64 keys: depth-5 tree max + 1 shuffle ----
    float m8[8];
#pragma unroll
    for (int i = 0; i < 8; ++i)
      m8[i] = fmaxf(fmaxf(s[i], s[i + 8]), fmaxf(s[i + 16], s[i + 24]));
    float tmax = fmaxf(fmaxf(fmaxf(m8[0], m8[1]), fmaxf(m8[2], m8[3])),
                       fmaxf(fmaxf(m8[4], m8[5]), fmaxf(m8[6], m8[7])));
    tmax = fmaxf(tmax, __shfl_xor(tmax, 32));

    if (!__all(tmax <= m + THR)) {      // T13 defer-max
      float mn2 = fmaxf(m, tmax);
      float a = __builtin_amdgcn_exp2f(m - mn2);
      m = mn2; l *= a;
      O[0] *= a; O[1] *= a;
    }

#pragma unroll
    for (int i = 0; i < 32; ++i) s[i] = __builtin_amdgcn_exp2f(s[i] - m);
    float a16[16];
#pragma unroll
    for (int i = 0; i < 16; ++i) a16[i] = s[i] + s[i + 16];
#pragma unroll
    for (int i = 0; i < 8; ++i) a16[i] += a16[i + 8];
#pragma unroll
    for (int i = 0; i < 4; ++i) a16[i] += a16[i + 4];
    float rs = (a16[0] + a16[1]) + (a16[2] + a16[3]);
    rs += __shfl_xor(rs, 32);
    l += rs;

    // ---- P -> bf16 -> PV fragments, fully in-register ----
    s16x8 pa[4];
#pragma unroll
    for (int sub = 0; sub < 2; ++sub) {
      unsigned pr[8];
#pragma unroll
      for (int i = 0; i < 8; ++i)
        pr[i] = pk2(s[16 * sub + 2 * i], s[16 * sub + 2 * i + 1]);
#pragma unroll
      for (int jc2 = 0; jc2 < 2; ++jc2) {
        unsigned x0, y0, x1, y1;
        pl32swap(pr[4 * jc2 + 0], pr[4 * jc2 + 2], x0, y0);
        pl32swap(pr[4 * jc2 + 1], pr[4 * jc2 + 3], x1, y1);
        u32x4 t; t[0] = x0; t[1] = x1; t[2] = y0; t[3] = y1;
        s16x8 f; __builtin_memcpy(&f, &t, 16);
        pa[2 * sub + jc2] = f;
      }
    }

    // ---- PV: O^T += V^T · P^T ----
    const unsigned short* vb = &Vt[cur][0];
    __builtin_amdgcn_s_setprio(1);
#pragma unroll
    for (int jc = 0; jc < 4; ++jc)
#pragma unroll
      for (int dn = 0; dn < 2; ++dn) {
        s16x8 vf = *(const s16x8*)(vb + (dn * 4 + jc) * 512 + lane * 8);
        O[dn] = __builtin_amdgcn_mfma_f32_32x32x16_bf16(vf, pa[jc], O[dn], 0, 0, 0);
      }
    __builtin_amdgcn_s_setprio(0);
  };

  // NT is even: 2x-unrolled ping-pong keeps all prefetch indexing static
  for (int jt = 0; jt < NT; jt += 2) {
    body(jt,     bvA, mnA, bvB, mnB);
    body(jt + 1, bvB, mnB, bvA, mnA);
  }

  // ---- epilogue ----
  const float inv = 1.0f / l;
  float* orow = out + qkvbase + (size_t)qr * Ddim;
#pragma unroll
  for (int dn = 0; dn < 2; ++dn)
#pragma unroll
    for (int c = 0; c < 4; ++c) {
      f32x4 o;
      o[0] = O[dn][4 * c + 0] * inv; o[1] = O[dn][4 * c + 1] * inv;
      o[2] = O[dn][4 * c + 2] * inv; o[3] = O[dn][4 * c + 3] * inv;
      *(f32x4*)(orow + 32 * dn + 8 * c + 4 * h2) = o;
    }
}

extern "C" void kernel_launch(void* const* d_in, const int* in_sizes, int n_in,
                              void* d_out, int out_size, void* d_ws, size_t ws_size,
                              hipStream_t stream) {
  const float* q    = (const float*)d_in[0];
  const float* k    = (const float*)d_in[1];
  const float* v    = (const float*)d_in[2];
  const int*   mask = (const int*)d_in[3];
  const float* taus = (const float*)d_in[4];
  const float* bias = (const float*)d_in[5];
  float* out = (float*)d_out;

  unsigned short* kimg = (unsigned short*)d_ws;           //  8,388,608 B
  unsigned short* vimg = kimg + 4194304;                  //  8,388,608 B
  float*          mneg = (float*)(vimg + 4194304);        //     16,384 B

  pack_kernel<<<dim3(NT, Bdim * Hdim), dim3(256), 0, stream>>>(
      k, v, mask, kimg, vimg, mneg);
  attn_kernel<<<dim3(Sdim / 128, Bdim * Hdim), dim3(256), 0, stream>>>(
      q, kimg, vimg, mneg, taus, bias, out);
}

// Round 2
// 108.735 us; speedup vs baseline: 1.3350x; 1.3350x over previous
//
#include <hip/hip_runtime.h>
#include <hip/hip_bf16.h>

#define Bdim 2
#define Hdim 16
#define Sdim 2048
#define Ddim 64
#define KVB 64
#define NT (Sdim / KVB)

typedef __attribute__((ext_vector_type(4)))  float    f32x4;
typedef __attribute__((ext_vector_type(16))) float    f32x16;
typedef __attribute__((ext_vector_type(2)))  unsigned u32x2;
typedef __attribute__((ext_vector_type(4)))  unsigned u32x4;
typedef __attribute__((ext_vector_type(8)))  short    s16x8;

#define NEGM   (-1.0e30f)
#define M_INIT (-30000.0f)
#define QS     0.18033688011112042f   // 0.125 * log2(e), folded into Q
#define L2E    1.4426950408889634f
#define THR    11.5f                  // defer-max threshold (log2 units ~ 8 nats)

typedef __attribute__((address_space(1))) void gv_t;
typedef __attribute__((address_space(3))) void lv_t;

// packed fp32x2 -> bf16x2 (RNE) — compiler emits v_cvt_pk_bf16_f32
static __device__ __forceinline__ unsigned pk2(float lo, float hi) {
  float2 t; t.x = lo; t.y = hi;
  __hip_bfloat162 h = __float22bfloat162_rn(t);
  unsigned u; __builtin_memcpy(&u, &h, 4); return u;
}

static __device__ __forceinline__ void pl32swap(unsigned a, unsigned b,
                                                unsigned &x, unsigned &y) {
#if __has_builtin(__builtin_amdgcn_permlane32_swap)
  typedef unsigned uv2 __attribute__((ext_vector_type(2)));
  uv2 r = __builtin_amdgcn_permlane32_swap(a, b, false, false);
  x = r[0]; y = r[1];
#else
  unsigned pa = (unsigned)__shfl_xor((int)a, 32);
  unsigned pb = (unsigned)__shfl_xor((int)b, 32);
  bool hi = (threadIdx.x & 32) != 0;
  x = hi ? pb : a;
  y = hi ? b : pa;
#endif
}

// ---------------- pre-pass: K/V^T -> bf16 fragment-linear tile images ------
// Image layout per (bh, jt): 512 chunks of 16B. chunk c: blk=c>>6, l=c&63.
// K  (blk = sub*4+kc): holds K [j=32sub+(l&31)] [elems 16kc+8(l>>5) .. +8]
// V^T(blk = dn*4+jc):  holds V^T[d=32dn+(l&31)] [j-elems 16jc+8(l>>5) .. +8]
__global__ __launch_bounds__(256, 2)
void pack_kernel(const float* __restrict__ k, const float* __restrict__ v,
                 const int* __restrict__ mask,
                 unsigned short* __restrict__ kimg,
                 unsigned short* __restrict__ vimg,
                 float* __restrict__ mneg)
{
  const int jt = blockIdx.x;   // 0..31
  const int bh = blockIdx.y;   // 0..31
  const int tid = threadIdx.x;
  const size_t base = ((size_t)bh) * Sdim * Ddim + (size_t)jt * KVB * Ddim;

  // K pack (2 chunks/thread)
  unsigned short* kout = kimg + ((size_t)(bh * NT + jt)) * 4096;
#pragma unroll
  for (int cc = 0; cc < 2; ++cc) {
    int c = tid + cc * 256;
    int blk = c >> 6, l = c & 63;
    int sub = blk >> 2, kc = blk & 3;
    int j = 32 * sub + (l & 31), e0 = 16 * kc + 8 * (l >> 5);
    const float* src = k + base + j * 64 + e0;
    f32x4 a = *(const f32x4*)src, b2 = *(const f32x4*)(src + 4);
    u32x4 t;
    t[0] = pk2(a[0], a[1]);  t[1] = pk2(a[2], a[3]);
    t[2] = pk2(b2[0], b2[1]); t[3] = pk2(b2[2], b2[3]);
    *(u32x4*)(kout + (size_t)c * 8) = t;
  }

  // V transpose pack via LDS
  __shared__ float Vl[64 * 64];
  {
    int r = tid >> 2, c4 = (tid & 3) * 16;
    const float* src = v + base + r * 64 + c4;
#pragma unroll
    for (int i = 0; i < 4; ++i)
      *(f32x4*)&Vl[r * 64 + c4 + 4 * i] = *(const f32x4*)(src + 4 * i);
  }
  __syncthreads();
  unsigned short* vout = vimg + ((size_t)(bh * NT + jt)) * 4096;
#pragma unroll
  for (int cc = 0; cc < 2; ++cc) {
    int c = tid + cc * 256;
    int blk = c >> 6, l = c & 63;
    int dn = blk >> 2, jc = blk & 3;
    int d = 32 * dn + (l & 31), jl0 = 16 * jc + 8 * (l >> 5);
    u32x4 t;
#pragma unroll
    for (int p = 0; p < 4; ++p)
      t[p] = pk2(Vl[(jl0 + 2 * p) * 64 + d], Vl[(jl0 + 2 * p + 1) * 64 + d]);
    *(u32x4*)(vout + (size_t)c * 8) = t;
  }

  // mneg
  if ((bh & 15) == 0 && tid < 64) {
    int b = bh >> 4;
    int j = jt * KVB + tid;
    mneg[b * Sdim + j] = mask[b * Sdim + j] ? 0.0f : NEGM;
  }
}

// ---------------- main kernel ----------------------------------------------
// 4 waves/block, 32 q-rows per wave. 32x32x16 MFMA, swapped operands.
// K/V^T staged via global_load_lds (16B async DMA), double-buffered.
// Pipeline discipline: ALL long-latency issues for tile jt+1 (bias prefetch
// into a 32-reg double-buffer set, K/V DMA) happen immediately AFTER tile
// jt's __syncthreads(), so they get a full phase (~QK+softmax+PV+barrier)
// of latency cover and the next barrier's implicit vmcnt(0) drain is free.
// Only mneg (256 B/tile, L1/L2-hot) is loaded in-phase, covered by QK.
// Register-frugal vs the failed R1 variant: one extra 32-VGPR bias set, no
// mneg prefetch, no manual waitcnts — no spills.
__global__ __launch_bounds__(256, 2)
void attn_kernel(const float* __restrict__ q,
                 unsigned short* __restrict__ kimg,
                 unsigned short* __restrict__ vimg,
                 const float* __restrict__ mneg,
                 const float* __restrict__ taus, const float* __restrict__ bias,
                 float* __restrict__ out)
{
  const int tid  = threadIdx.x;
  const int wave = tid >> 6;
  const int lane = tid & 63;
  const int h2   = lane >> 5;
  const int q5   = lane & 31;

  const int bh = blockIdx.y;
  const int b  = bh >> 4, h = bh & 15;
  const int iw = blockIdx.x * 128 + wave * 32;
  const int qr = iw + q5;

  __shared__ __align__(16) unsigned short Kl[2][4096];
  __shared__ __align__(16) unsigned short Vt[2][4096];

  const float ntau = -taus[h] * L2E;
  const size_t qkvbase = ((size_t)bh) * Sdim * Ddim;
  const float* biasb = bias + (size_t)b * Sdim * Sdim + (size_t)qr * Sdim;
  const float* mnegb = mneg + b * Sdim;

  // Q B-fragments: qf[kc] = Q[qr][16kc + 8h2 + t]*QS
  s16x8 qf[4];
  {
    const float* qrow = q + qkvbase + (size_t)qr * Ddim + 8 * h2;
#pragma unroll
    for (int kc = 0; kc < 4; ++kc) {
      f32x4 a = *(const f32x4*)(qrow + 16 * kc);
      f32x4 c = *(const f32x4*)(qrow + 16 * kc + 4);
      u32x4 t;
      t[0] = pk2(a[0] * QS, a[1] * QS); t[1] = pk2(a[2] * QS, a[3] * QS);
      t[2] = pk2(c[0] * QS, c[1] * QS); t[3] = pk2(c[2] * QS, c[3] * QS);
      s16x8 f; __builtin_memcpy(&f, &t, 16); qf[kc] = f;
    }
  }

  // async stage tile jt into buffer buf: 4 global_load_lds per wave
  auto stage = [&](int jt, int buf) {
    size_t tb = ((size_t)(bh * NT + jt)) * 4096 + wave * 1024 + lane * 8;
    int lo = wave * 1024;
#pragma unroll
    for (int i = 0; i < 2; ++i) {
      __builtin_amdgcn_global_load_lds((gv_t*)(kimg + tb + i * 512),
                                       (lv_t*)&Kl[buf][lo + i * 512], 16, 0, 0);
      __builtin_amdgcn_global_load_lds((gv_t*)(vimg + tb + i * 512),
                                       (lv_t*)&Vt[buf][lo + i * 512], 16, 0, 0);
    }
  };

  f32x16 O[2];
  O[0] = (f32x16)(0.0f); O[1] = (f32x16)(0.0f);
  float m = M_INIT, l = 0.0f;

  // bias prefetch: double-buffered, 32 VGPRs per set (bias only!)
  f32x4 bvA[2][4], bvB[2][4];

  stage(0, 0);
  // prologue: bias for tile 0 into set A
#pragma unroll
  for (int sub = 0; sub < 2; ++sub)
#pragma unroll
    for (int c = 0; c < 4; ++c)
      bvA[sub][c] = *(const f32x4*)(biasb + 32 * sub + 8 * c + 4 * h2);

  // body: process tile jt with bias in bvC; prefetch tile jt+1's bias to bvN
  auto body = [&](int jt, f32x4 (&bvC)[2][4], f32x4 (&bvN)[2][4]) {
    const int cur = jt & 1;
    const int j0  = jt * KVB;

    __syncthreads();   // vmcnt(0)+lgkmcnt(0)+barrier: everything in flight
                       // was issued a full phase ago — drain is ~free

    // ---- issue next phase's long-latency ops FIRST (full-phase cover) ----
    if (jt + 1 < NT) {
      const int j0n = (jt + 1) * KVB;
#pragma unroll
      for (int sub = 0; sub < 2; ++sub)
#pragma unroll
        for (int c = 0; c < 4; ++c)
          bvN[sub][c] = *(const f32x4*)(biasb + j0n + 32 * sub + 8 * c + 4 * h2);
      stage(jt + 1, cur ^ 1);
    }

    // ---- mneg for current tile (L1/L2-hot, covered by QK) ----
    f32x4 mn[2][4];
#pragma unroll
    for (int sub = 0; sub < 2; ++sub)
#pragma unroll
      for (int c = 0; c < 4; ++c)
        mn[sub][c] = *(const f32x4*)(mnegb + j0 + 32 * sub + 8 * c + 4 * h2);

    // ---- QK^T: acc[sub] = S^T[j][q], log2-scaled ----
    const unsigned short* kb = &Kl[cur][0];
    f32x16 acc[2];
    acc[0] = (f32x16)(0.0f); acc[1] = (f32x16)(0.0f);
    __builtin_amdgcn_s_setprio(1);
#pragma unroll
    for (int sub = 0; sub < 2; ++sub)
#pragma unroll
      for (int kc = 0; kc < 4; ++kc) {
        s16x8 kf = *(const s16x8*)(kb + (sub * 4 + kc) * 512 + lane * 8);
        acc[sub] = __builtin_amdgcn_mfma_f32_32x32x16_bf16(kf, qf[kc], acc[sub], 0, 0, 0);
      }
    __builtin_amdgcn_s_setprio(0);

    // ---- fold addv (bias prefetched last phase; mneg just covered) ----
    f32x4 addv[2][4];
#pragma unroll
    for (int sub = 0; sub < 2; ++sub)
#pragma unroll
      for (int c = 0; c < 4; ++c)
        addv[sub][c] = ntau * bvC[sub][c] + mn[sub][c];

    // ---- scores (log2 domain) ----
    float s[32];
#pragma unroll
    for (int sub = 0; sub < 2; ++sub)
#pragma unroll
      for (int r = 0; r < 16; ++r)
        s[16 * sub + r] = acc[sub][r] + addv[sub][r >> 2][r & 3];

    // ---- online softmax over 64 keys: depth-5 tree max + 1 shuffle ----
    float m8[8];
#pragma unroll
    for (int i = 0; i < 8; ++i)
      m8[i] = fmaxf(fmaxf(s[i], s[i + 8]), fmaxf(s[i + 16], s[i + 24]));
    float tmax = fmaxf(fmaxf(fmaxf(m8[0], m8[1]), fmaxf(m8[2], m8[3])),
                       fmaxf(fmaxf(m8[4], m8[5]), fmaxf(m8[6], m8[7])));
    tmax = fmaxf(tmax, __shfl_xor(tmax, 32));

    if (!__all(tmax <= m + THR)) {      // T13 defer-max
      float mn2 = fmaxf(m, tmax);
      float a = __builtin_amdgcn_exp2f(m - mn2);
      m = mn2; l *= a;
      O[0] *= a; O[1] *= a;
    }

#pragma unroll
    for (int i = 0; i < 32; ++i) s[i] = __builtin_amdgcn_exp2f(s[i] - m);
    float a16[16];
#pragma unroll
    for (int i = 0; i < 16; ++i) a16[i] = s[i] + s[i + 16];
#pragma unroll
    for (int i = 0; i < 8; ++i) a16[i] += a16[i + 8];
#pragma unroll
    for (int i = 0; i < 4; ++i) a16[i] += a16[i + 4];
    float rs = (a16[0] + a16[1]) + (a16[2] + a16[3]);
    rs += __shfl_xor(rs, 32);
    l += rs;

    // ---- P -> bf16 -> PV fragments, fully in-register ----
    s16x8 pa[4];
#pragma unroll
    for (int sub = 0; sub < 2; ++sub) {
      unsigned pr[8];
#pragma unroll
      for (int i = 0; i < 8; ++i)
        pr[i] = pk2(s[16 * sub + 2 * i], s[16 * sub + 2 * i + 1]);
#pragma unroll
      for (int jc2 = 0; jc2 < 2; ++jc2) {
        unsigned x0, y0, x1, y1;
        pl32swap(pr[4 * jc2 + 0], pr[4 * jc2 + 2], x0, y0);
        pl32swap(pr[4 * jc2 + 1], pr[4 * jc2 + 3], x1, y1);
        u32x4 t; t[0] = x0; t[1] = x1; t[2] = y0; t[3] = y1;
        s16x8 f; __builtin_memcpy(&f, &t, 16);
        pa[2 * sub + jc2] = f;
      }
    }

    // ---- PV: O^T += V^T · P^T ----
    const unsigned short* vb = &Vt[cur][0];
    __builtin_amdgcn_s_setprio(1);
#pragma unroll
    for (int jc = 0; jc < 4; ++jc)
#pragma unroll
      for (int dn = 0; dn < 2; ++dn) {
        s16x8 vf = *(const s16x8*)(vb + (dn * 4 + jc) * 512 + lane * 8);
        O[dn] = __builtin_amdgcn_mfma_f32_32x32x16_bf16(vf, pa[jc], O[dn], 0, 0, 0);
      }
    __builtin_amdgcn_s_setprio(0);
  };

  // NT is even: 2x-unrolled ping-pong keeps all prefetch indexing static
  for (int jt = 0; jt < NT; jt += 2) {
    body(jt,     bvA, bvB);
    body(jt + 1, bvB, bvA);
  }

  // ---- epilogue ----
  const float inv = 1.0f / l;
  float* orow = out + qkvbase + (size_t)qr * Ddim;
#pragma unroll
  for (int dn = 0; dn < 2; ++dn)
#pragma unroll
    for (int c = 0; c < 4; ++c) {
      f32x4 o;
      o[0] = O[dn][4 * c + 0] * inv; o[1] = O[dn][4 * c + 1] * inv;
      o[2] = O[dn][4 * c + 2] * inv; o[3] = O[dn][4 * c + 3] * inv;
      *(f32x4*)(orow + 32 * dn + 8 * c + 4 * h2) = o;
    }
}

extern "C" void kernel_launch(void* const* d_in, const int* in_sizes, int n_in,
                              void* d_out, int out_size, void* d_ws, size_t ws_size,
                              hipStream_t stream) {
  const float* q    = (const float*)d_in[0];
  const float* k    = (const float*)d_in[1];
  const float* v    = (const float*)d_in[2];
  const int*   mask = (const int*)d_in[3];
  const float* taus = (const float*)d_in[4];
  const float* bias = (const float*)d_in[5];
  float* out = (float*)d_out;

  unsigned short* kimg = (unsigned short*)d_ws;           //  8,388,608 B
  unsigned short* vimg = kimg + 4194304;                  //  8,388,608 B
  float*          mneg = (float*)(vimg + 4194304);        //     16,384 B

  pack_kernel<<<dim3(NT, Bdim * Hdim), dim3(256), 0, stream>>>(
      k, v, mask, kimg, vimg, mneg);
  attn_kernel<<<dim3(Sdim / 128, Bdim * Hdim), dim3(256), 0, stream>>>(
      q, kimg, vimg, mneg, taus, bias, out);
}